// Round 12
// baseline (230.615 us; speedup 1.0000x reference)
//
#include <hip/hip_runtime.h>
#include <hip/hip_bf16.h>

#define D 64
#define BSHIFT 8           // 256 nodes per bucket
#define BNODES 256
#define BCAP 4096          // edge capacity per bucket region (exp 2558, +30 sigma)
#define PTILE 2048         // edges per partition tile (489 blocks -> full CU coverage)

typedef __attribute__((ext_vector_type(8))) short short8;
typedef __attribute__((ext_vector_type(4))) float float4v;

__device__ __forceinline__ float bf16u_to_f32(unsigned short u) {
  union { unsigned int i; float f; } c;
  c.i = ((unsigned int)u) << 16;
  return c.f;
}

__device__ __forceinline__ unsigned short f32_to_bf16u(float f) {
  union { float f; unsigned int u; } c;
  c.f = f;
  unsigned int r = (c.u + 0x7fffu + ((c.u >> 16) & 1u)) >> 16;  // RNE
  return (unsigned short)r;
}

// ---- per-wave dtype detection (round-12: replaces the serial 1-block
// k_probe kernel; ~8 L2-hot loads + __any per wave, wave-uniform result) ----
// f32: weights reinterpreted as bf16 decode to huge/NaN if underlying fp32.
__device__ __forceinline__ int wave_f32flag(const void* W) {
  const unsigned short* wb = (const unsigned short*)W;
  int lane = threadIdx.x & 63;
  bool big = false;
  for (int i = lane; i < 512; i += 64) {
    float v = bf16u_to_f32(wb[i]);
    if (!(fabsf(v) < 100.f)) big = true;  // NaN lands here too
  }
  return __any(big) ? 1 : 0;
}
// i64: odd 32-bit words of the first 64 index pairs all zero iff int64.
__device__ __forceinline__ int wave_i64flag(const void* ei) {
  const int* e32 = (const int*)ei;
  int lane = threadIdx.x & 63;
  bool nz = (e32[2 * lane + 1] != 0);
  return __any(nz) ? 0 : 1;
}

// ---------------- weight prep + cursor init (parallel) ----------------

__global__ __launch_bounds__(256) void k_prep(
    const void* __restrict__ Ws, const void* __restrict__ Wout,
    const void* __restrict__ bs, const void* __restrict__ bout,
    unsigned short* __restrict__ WT, float* __restrict__ biasf,
    int* __restrict__ bucket_cursor) {
  int f32 = wave_f32flag(Ws);
  int gid = blockIdx.x * 256 + threadIdx.x;
  int stride = gridDim.x * 256;

  for (int i = gid; i < 512; i += stride) bucket_cursor[i] = i * BCAP;

  // transpose 4 weight matrices into WT[l][n][k] (bf16)
  for (int i = gid; i < 4 * 4096; i += stride) {
    int l = i >> 12;
    int r = i & 4095;
    int k = r >> 6;
    int nn = r & 63;
    unsigned short v;
    if (l < 3) {
      v = f32 ? f32_to_bf16u(((const float*)Ws)[l * 4096 + r])
              : ((const unsigned short*)Ws)[l * 4096 + r];
    } else {
      v = f32 ? f32_to_bf16u(((const float*)Wout)[r])
              : ((const unsigned short*)Wout)[r];
    }
    WT[l * 4096 + nn * 64 + k] = v;
  }
  // biases -> fp32
  for (int i = gid; i < 4 * 64; i += stride) {
    int l = i >> 6;
    int j = i & 63;
    float v;
    if (l < 3)
      v = f32 ? ((const float*)bs)[l * 64 + j]
              : bf16u_to_f32(((const unsigned short*)bs)[l * 64 + j]);
    else
      v = f32 ? ((const float*)bout)[j]
              : bf16u_to_f32(((const unsigned short*)bout)[j]);
    biasf[i] = v;
  }
}

// ---------------- bucketed partition (fixed-capacity regions) ----------------

__global__ __launch_bounds__(256) void k_partition(
    const void* __restrict__ ei, int* __restrict__ bucket_cursor,
    int* __restrict__ packed, int e) {
  __shared__ int lhist[512];
  __shared__ int lbase[512];
  int tid = threadIdx.x;
  int t0 = blockIdx.x * PTILE;
  int tend = min(t0 + PTILE, e);
  if (t0 >= e) return;
  int i64 = wave_i64flag(ei);

  for (int b = tid; b < 512; b += 256) lhist[b] = 0;
  __syncthreads();

  if (i64) {
    const long long* dst = (const long long*)ei + e;
    for (int i = t0 + tid; i < tend; i += 256)
      atomicAdd(&lhist[((int)dst[i]) >> BSHIFT], 1);
  } else {
    const int* dst = (const int*)ei + e;
    for (int i = t0 + tid; i < tend; i += 256)
      atomicAdd(&lhist[dst[i] >> BSHIFT], 1);
  }
  __syncthreads();

  for (int b = tid; b < 512; b += 256) {
    int c = lhist[b];
    lbase[b] = c ? atomicAdd(&bucket_cursor[b], c) : 0;
    lhist[b] = 0;  // reuse as rank counter
  }
  __syncthreads();

  if (i64) {
    const long long* srcp = (const long long*)ei;
    const long long* dstp = srcp + e;
    for (int i = t0 + tid; i < tend; i += 256) {
      int s = (int)srcp[i];
      int d = (int)dstp[i];
      int b = d >> BSHIFT;
      int r = atomicAdd(&lhist[b], 1);
      packed[lbase[b] + r] = (s << BSHIFT) | (d & (BNODES - 1));
    }
  } else {
    const int* srcp = (const int*)ei;
    const int* dstp = srcp + e;
    for (int i = t0 + tid; i < tend; i += 256) {
      int s = srcp[i];
      int d = dstp[i];
      int b = d >> BSHIFT;
      int r = atomicAdd(&lhist[b], 1);
      packed[lbase[b] + r] = (s << BSHIFT) | (d & (BNODES - 1));
    }
  }
}

// One block per bucket: LDS counting sort -> per-node src list (grouped by
// dst) in the bucket's csr region, rowrange (beg,end), dinv.
__global__ __launch_bounds__(256) void k_sort_csr(
    const int* __restrict__ packed, const int* __restrict__ bucket_cursor,
    int* __restrict__ csr, int2* __restrict__ rowrange,
    float* __restrict__ dinv, int n) {
  __shared__ int lcnt[BNODES];
  __shared__ int lofs[BNODES];
  __shared__ int sbuf[BNODES];
  int tid = threadIdx.x;
  int bucket = blockIdx.x;
  int node0 = bucket << BSHIFT;
  int nodes = min(BNODES, n - node0);
  int s0 = bucket * BCAP;
  int s1 = bucket_cursor[bucket];  // region end after partition
  lcnt[tid] = 0;
  __syncthreads();
  for (int i = s0 + tid; i < s1; i += 256)
    atomicAdd(&lcnt[packed[i] & (BNODES - 1)], 1);
  __syncthreads();
  int v = lcnt[tid];
  sbuf[tid] = v;
  __syncthreads();
  for (int off = 1; off < BNODES; off <<= 1) {
    int tv = (tid >= off) ? sbuf[tid - off] : 0;
    __syncthreads();
    sbuf[tid] += tv;
    __syncthreads();
  }
  int excl = sbuf[tid] - v;
  lofs[tid] = excl;
  lcnt[tid] = 0;  // reuse as rank counter
  if (tid < nodes) {
    rowrange[node0 + tid] = make_int2(s0 + excl, s0 + excl + v);
    dinv[node0 + tid] = rsqrtf((float)(v + 1));  // +1 = self loop
  }
  __syncthreads();
  for (int i = s0 + tid; i < s1; i += 256) {
    int pk = packed[i];
    int ld = pk & (BNODES - 1);
    int r = atomicAdd(&lcnt[ld], 1);
    csr[s0 + lofs[ld] + r] = pk >> BSHIFT;
  }
}

// ---------------- z0 = dinv * x0 (bf16), handles fp32/bf16 input ----------------

__global__ __launch_bounds__(256) void k_scale(
    const void* __restrict__ x0, const void* __restrict__ Ws,
    const float* __restrict__ dinv, ushort4* __restrict__ z, int n16) {
  int f32 = wave_f32flag(Ws);
  int i = blockIdx.x * 256 + threadIdx.x;
  int stride = gridDim.x * 256;
  for (; i < n16; i += stride) {
    float d = dinv[i >> 4];
    ushort4 o;
    if (f32) {
      float4 v = ((const float4*)x0)[i];
      o.x = f32_to_bf16u(d * v.x);
      o.y = f32_to_bf16u(d * v.y);
      o.z = f32_to_bf16u(d * v.z);
      o.w = f32_to_bf16u(d * v.w);
    } else {
      ushort4 v = ((const ushort4*)x0)[i];
      o.x = f32_to_bf16u(d * bf16u_to_f32(v.x));
      o.y = f32_to_bf16u(d * bf16u_to_f32(v.y));
      o.z = f32_to_bf16u(d * bf16u_to_f32(v.z));
      o.w = f32_to_bf16u(d * bf16u_to_f32(v.w));
    }
    z[i] = o;
  }
}

// ---------------- fused layer ----------------
// y = dinv_dst*(z_dst + sum z_src); out = relu(yW+b) [optionally * dinv].
// One block per 16-node tile; r6 gather/merge structure (plateau-validated:
// addr-cut r3 +15%, DS-merge r6 +10%; occupancy x2 / persistent pipeline /
// slot-table front-end / deg-skip / sc0 L1-bypass all null or negative ->
// gather throughput = shared outstanding-request capacity / L2-L3 latency).
// r11: layer 2 chains the final projection GEMM in-kernel (x3 -> ybf2,
// barrier, 2 MFMAs with Wout frags, store d_out) -- saved 25MB round-trip.
// r12: output dtype flag computed per-wave from WsP (k_probe deleted).
// Spill tripwire: WRITE_SIZE ~12.5MB. Bank tripwire: SQ_LDS_BANK_CONFLICT ~0.
__global__ __launch_bounds__(256, 4) void k_fused(
    const unsigned short* __restrict__ z, const int2* __restrict__ rowrange,
    const int* __restrict__ csr, const float* __restrict__ dinv,
    const unsigned short* __restrict__ WT, const float* __restrict__ biasf,
    unsigned short* __restrict__ out, int n, int scale_out,
    const unsigned short* __restrict__ WTf, const float* __restrict__ biasff,
    void* __restrict__ fout, const void* __restrict__ WsP) {
  __shared__ __align__(16) float part[4 * 2048];  // [wave][node][group][ch]
  __shared__ unsigned short ybf[16 * 80];
  __shared__ unsigned short ybf2[16 * 80];
  int tid = threadIdx.x;
  int lane = tid & 63;
  int w = tid >> 6;   // wave id = output col-tile
  int q = lane >> 4;  // phase-2 quarter
  int f = lane & 15;  // phase-2 frag row
  int h = lane & 7;   // 16B slot within a 128B z row
  int g8 = lane >> 3; // 8-lane group = edge slot group

  // B-frags for this wave's column tile
  short8 b0 = *(const short8*)(WT + (size_t)(f + 16 * w) * 64 + q * 8);
  short8 b1 = *(const short8*)(WT + (size_t)(f + 16 * w) * 64 + 32 + q * 8);
  // final-GEMM frags (layer 2 only; wave-uniform branch)
  short8 c0 = {0, 0, 0, 0, 0, 0, 0, 0};
  short8 c1 = {0, 0, 0, 0, 0, 0, 0, 0};
  float bvf = 0.f;
  int f32o = 0;
  if (fout != nullptr) {
    c0 = *(const short8*)(WTf + (size_t)(f + 16 * w) * 64 + q * 8);
    c1 = *(const short8*)(WTf + (size_t)(f + 16 * w) * 64 + 32 + q * 8);
    bvf = biasff[16 * w + f];
    f32o = wave_f32flag(WsP);
  }

  int row0 = blockIdx.x * 16;
  int base_node = row0 + w * 4;
  const short8* z8 = (const short8*)z;

  // --- rowrange: one 8-lane load, broadcast via shfl ---
  int rrw = 0;
  if (lane < 8) rrw = ((const int*)rowrange)[(size_t)base_node * 2 + lane];
  int rx0 = __shfl(rrw, 0, 64);
  int ry0 = __shfl(rrw, 1, 64);
  int rx1 = __shfl(rrw, 2, 64);
  int ry1 = __shfl(rrw, 3, 64);
  int rx2 = __shfl(rrw, 4, 64);
  int ry2 = __shfl(rrw, 5, 64);
  int rx3 = __shfl(rrw, 6, 64);
  int ry3 = __shfl(rrw, 7, 64);
  int deg0 = ry0 - rx0;
  int deg1 = ry1 - rx1;
  int deg2 = ry2 - rx2;
  int deg3 = ry3 - rx3;

  // --- index table: lane (jx*16+m) holds slot m of node jx ---
  // slot 0 = self, slots 1..15 = first 15 csr edges (clamped dups if short)
  int jx = lane >> 4;
  int m = lane & 15;
  int rxj = (jx & 2) ? ((jx & 1) ? rx3 : rx2) : ((jx & 1) ? rx1 : rx0);
  int dgj = (jx & 2) ? ((jx & 1) ? deg3 : deg2) : ((jx & 1) ? deg1 : deg0);
  int coff = (m >= 1 && m <= dgj) ? (m - 1) : 0;
  int idx = csr[rxj + coff];
  if (m == 0) idx = base_node + jx;

  // --- phase 1: 8 gather instrs, 8 edges each (16B/lane, 8 lanes/row) ---
  float a0[8] = {0, 0, 0, 0, 0, 0, 0, 0};
  float a1[8] = {0, 0, 0, 0, 0, 0, 0, 0};
  float a2[8] = {0, 0, 0, 0, 0, 0, 0, 0};
  float a3[8] = {0, 0, 0, 0, 0, 0, 0, 0};

  short8 g[8];
#pragma unroll
  for (int t = 0; t < 8; t++) {
    int u = ((t & 1) << 3) + g8;                 // slot 0..15
    int sl = ((t >> 1) << 4) + u;                // table holder lane
    int s = __shfl(idx, sl, 64);
    g[t] = z8[(size_t)s * 8 + h];
  }
#pragma unroll
  for (int t = 0; t < 8; t++) {
    int u = ((t & 1) << 3) + g8;
    const int j = t >> 1;
    int dg = (j == 0) ? deg0 : (j == 1) ? deg1 : (j == 2) ? deg2 : deg3;
    float vm = (u <= dg) ? 1.f : 0.f;
    float* aj = (j == 0) ? a0 : (j == 1) ? a1 : (j == 2) ? a2 : a3;
#pragma unroll
    for (int c = 0; c < 8; c++)
      aj[c] += vm * bf16u_to_f32((unsigned short)g[t][c]);
  }

  // --- rare tail: deg > 15, 8 edges per round ---
#pragma unroll
  for (int j = 0; j < 4; j++) {
    int rx = (j == 0) ? rx0 : (j == 1) ? rx1 : (j == 2) ? rx2 : rx3;
    int dg = (j == 0) ? deg0 : (j == 1) ? deg1 : (j == 2) ? deg2 : deg3;
    float* aj = (j == 0) ? a0 : (j == 1) ? a1 : (j == 2) ? a2 : a3;
    for (int e0 = 15; e0 < dg; e0 += 8) {
      int e = e0 + g8;
      bool vv = e < dg;
      int s = csr[rx + (vv ? e : 0)];
      short8 tv = z8[(size_t)s * 8 + h];
      float vm = vv ? 1.f : 0.f;
#pragma unroll
      for (int c = 0; c < 8; c++)
        aj[c] += vm * bf16u_to_f32((unsigned short)tv[c]);
    }
  }

  // --- merge the 8 groups via per-wave XOR-swizzled LDS partials ---
  // layout: byte = w*8192 + j*2048 + g*256 + ((gi ^ g) << 4), gi = ch>>2
  char* pb = (char*)part + (w << 13);
  {
    int base_wg = g8 << 8;  // g8*256
#pragma unroll
    for (int j = 0; j < 4; j++) {
      const float* aj = (j == 0) ? a0 : (j == 1) ? a1 : (j == 2) ? a2 : a3;
      int jb = j << 11;
      *(float4*)(pb + jb + base_wg + ((((2 * h) ^ g8)) << 4)) =
          make_float4(aj[0], aj[1], aj[2], aj[3]);
      *(float4*)(pb + jb + base_wg + ((((2 * h + 1) ^ g8)) << 4)) =
          make_float4(aj[4], aj[5], aj[6], aj[7]);
    }
  }
  // read back: lane -> node jr = lane>>4, channels 4*gr..4*gr+3 (gr=lane&15)
  int jr = lane >> 4;
  int gr = lane & 15;
  float s0 = 0.f, s1 = 0.f, s2 = 0.f, s3 = 0.f;
#pragma unroll
  for (int gg = 0; gg < 8; gg++) {
    float4 v = *(const float4*)(pb + (jr << 11) + (gg << 8) + ((gr ^ gg) << 4));
    s0 += v.x;
    s1 += v.y;
    s2 += v.z;
    s3 += v.w;
  }
  {
    float dv = dinv[base_node + jr];
    unsigned int w0 = (unsigned int)f32_to_bf16u(dv * s0) |
                      ((unsigned int)f32_to_bf16u(dv * s1) << 16);
    unsigned int w1 = (unsigned int)f32_to_bf16u(dv * s2) |
                      ((unsigned int)f32_to_bf16u(dv * s3) << 16);
    *(uint2*)&ybf[(w * 4 + jr) * 80 + 4 * gr] = make_uint2(w0, w1);
  }
  __syncthreads();

  // --- phase 2: MFMA yW for this wave's 16 columns ---
  short8 fa0 = *(const short8*)&ybf[f * 80 + q * 8];
  short8 fa1 = *(const short8*)&ybf[f * 80 + 32 + q * 8];
  float4v zz = {0.f, 0.f, 0.f, 0.f};
  float4v acc = __builtin_amdgcn_mfma_f32_16x16x32_bf16(fa0, b0, zz, 0, 0, 0);
  acc = __builtin_amdgcn_mfma_f32_16x16x32_bf16(fa1, b1, acc, 0, 0, 0);

  float bv = biasf[16 * w + f];
  if (fout == nullptr) {
    if (scale_out) {
      float4 dv4 = *(const float4*)(dinv + row0 + q * 4);
      float d[4] = {dv4.x, dv4.y, dv4.z, dv4.w};
#pragma unroll
      for (int reg = 0; reg < 4; reg++) {
        int row = row0 + q * 4 + reg;
        if (row < n)
          out[(size_t)row * 64 + 16 * w + f] =
              f32_to_bf16u(d[reg] * fmaxf(acc[reg] + bv, 0.f));
      }
    } else {
#pragma unroll
      for (int reg = 0; reg < 4; reg++) {
        int row = row0 + q * 4 + reg;
        if (row < n)
          out[(size_t)row * 64 + 16 * w + f] =
              f32_to_bf16u(fmaxf(acc[reg] + bv, 0.f));
      }
    }
  } else {
    // --- chained final projection: x3 -> ybf2, barrier, x3 @ Wout + bout ---
#pragma unroll
    for (int reg = 0; reg < 4; reg++) {
      int r = q * 4 + reg;
      ybf2[r * 80 + 16 * w + f] = f32_to_bf16u(fmaxf(acc[reg] + bv, 0.f));
    }
    __syncthreads();
    short8 ga0 = *(const short8*)&ybf2[f * 80 + q * 8];
    short8 ga1 = *(const short8*)&ybf2[f * 80 + 32 + q * 8];
    float4v acc2 =
        __builtin_amdgcn_mfma_f32_16x16x32_bf16(ga0, c0, zz, 0, 0, 0);
    acc2 = __builtin_amdgcn_mfma_f32_16x16x32_bf16(ga1, c1, acc2, 0, 0, 0);
    if (f32o) {
      float* op = (float*)fout;
#pragma unroll
      for (int reg = 0; reg < 4; reg++) {
        int row = row0 + q * 4 + reg;
        if (row < n) op[(size_t)row * 64 + 16 * w + f] = acc2[reg] + bvf;
      }
    } else {
      unsigned short* op = (unsigned short*)fout;
#pragma unroll
      for (int reg = 0; reg < 4; reg++) {
        int row = row0 + q * 4 + reg;
        if (row < n)
          op[(size_t)row * 64 + 16 * w + f] = f32_to_bf16u(acc2[reg] + bvf);
      }
    }
  }
}

// ---------------- launch ----------------

extern "C" void kernel_launch(void* const* d_in, const int* in_sizes, int n_in,
                              void* d_out, int out_size, void* d_ws,
                              size_t ws_size, hipStream_t stream) {
  const void* x0 = d_in[0];
  const void* ei = d_in[1];
  const void* Ws = d_in[2];
  const void* bs = d_in[3];
  const void* Wout = d_in[4];
  const void* bout = d_in[5];

  const int N = in_sizes[0] / D;  // 100000
  const int E = in_sizes[1] / 2;  // 1000000
  const int NBUC = (N + BNODES - 1) >> BSHIFT;  // 391
  const int NT = (N + 15) / 16;  // 6250 row tiles

  char* p = (char*)d_ws;
  auto alloc = [&](size_t bytes) {
    char* r = p;
    p += (bytes + 511) & ~(size_t)511;
    return r;
  };
  int* bucket_cursor = (int*)alloc(512 * 4);
  int* packed = (int*)alloc((size_t)512 * BCAP * 4);
  int* csr = (int*)alloc((size_t)512 * BCAP * 4);
  int2* rowrange = (int2*)alloc((size_t)N * 8);
  float* dinv = (float*)alloc((size_t)N * 4);
  unsigned short* WT = (unsigned short*)alloc(4 * 4096 * 2);
  float* biasf = (float*)alloc(4 * 64 * 4);
  unsigned short* za = (unsigned short*)alloc((size_t)N * D * 2);
  unsigned short* zb = (unsigned short*)alloc((size_t)N * D * 2);
  (void)ws_size;
  (void)n_in;
  (void)out_size;

  k_prep<<<32, 256, 0, stream>>>(Ws, Wout, bs, bout, WT, biasf, bucket_cursor);
  int ptiles = (E + PTILE - 1) / PTILE;
  k_partition<<<ptiles, 256, 0, stream>>>(ei, bucket_cursor, packed, E);
  k_sort_csr<<<NBUC, 256, 0, stream>>>(packed, bucket_cursor, csr, rowrange,
                                       dinv, N);
  k_scale<<<1024, 256, 0, stream>>>(x0, Ws, dinv, (ushort4*)za, N * 16);

  // layer 0: za -> zb (z'), layer 1: zb -> za (z'),
  // layer 2: za -> (x3 in LDS) -> chained final GEMM -> d_out
  k_fused<<<NT, 256, 0, stream>>>(za, rowrange, csr, dinv, WT + 0 * 4096,
                                  biasf + 0 * 64, zb, N, 1, nullptr, nullptr,
                                  nullptr, nullptr);
  k_fused<<<NT, 256, 0, stream>>>(zb, rowrange, csr, dinv, WT + 1 * 4096,
                                  biasf + 1 * 64, za, N, 1, nullptr, nullptr,
                                  nullptr, nullptr);
  k_fused<<<NT, 256, 0, stream>>>(za, rowrange, csr, dinv, WT + 2 * 4096,
                                  biasf + 2 * 64, zb, N, 0, WT + 3 * 4096,
                                  biasf + 3 * 64, d_out, Ws);
}

// Round 13
// 221.285 us; speedup vs baseline: 1.0422x; 1.0422x over previous
//
#include <hip/hip_runtime.h>
#include <hip/hip_bf16.h>

#define D 64
#define BSHIFT 8           // 256 nodes per bucket
#define BNODES 256
#define BCAP 4096          // edge capacity per bucket region (exp 2558, +30 sigma)
#define PTILE 2048         // edges per partition tile (489 blocks -> full CU coverage)

typedef __attribute__((ext_vector_type(8))) short short8;
typedef __attribute__((ext_vector_type(4))) float float4v;

// flags[0] = 1 if float tensors are fp32 (else bf16)
// flags[1] = 1 if edge_index is int64 (else int32)

__device__ __forceinline__ float bf16u_to_f32(unsigned short u) {
  union { unsigned int i; float f; } c;
  c.i = ((unsigned int)u) << 16;
  return c.f;
}

__device__ __forceinline__ unsigned short f32_to_bf16u(float f) {
  union { float f; unsigned int u; } c;
  c.f = f;
  unsigned int r = (c.u + 0x7fffu + ((c.u >> 16) & 1u)) >> 16;  // RNE
  return (unsigned short)r;
}

// ---------------- probe dtypes ----------------
// r12 lesson: computing these per-wave inside k_fused changed its codegen
// (VGPR 64->52, SGPR 48->112) and re-serialized the gather flight (+10.9us).
// Keep the tiny serial probe kernel; its launch cost is noise by comparison.

__global__ void k_probe(const void* W, const void* ei, int* flags) {
  int lane = threadIdx.x & 63;
  const unsigned short* wb = (const unsigned short*)W;
  bool big = false;
  for (int i = lane; i < 512; i += 64) {
    float v = bf16u_to_f32(wb[i]);
    if (!(fabsf(v) < 100.f)) big = true;  // NaN lands here too
  }
  int anybig = __any(big);
  const int* e32 = (const int*)ei;
  bool nz = (e32[2 * lane + 1] != 0);  // odd words of first 64 pairs
  int anynz = __any(nz);
  if (threadIdx.x == 0) {
    flags[0] = anybig ? 1 : 0;  // huge magnitudes => data is actually fp32
    flags[1] = anynz ? 0 : 1;   // all-zero odd words => int64
  }
}

// ---------------- weight prep + cursor init (parallel) ----------------

__global__ __launch_bounds__(256) void k_prep(
    const void* __restrict__ Ws, const void* __restrict__ Wout,
    const void* __restrict__ bs, const void* __restrict__ bout,
    const int* __restrict__ flags, unsigned short* __restrict__ WT,
    float* __restrict__ biasf, int* __restrict__ bucket_cursor) {
  int f32 = flags[0];
  int gid = blockIdx.x * 256 + threadIdx.x;
  int stride = gridDim.x * 256;

  for (int i = gid; i < 512; i += stride) bucket_cursor[i] = i * BCAP;

  // transpose 4 weight matrices into WT[l][n][k] (bf16)
  for (int i = gid; i < 4 * 4096; i += stride) {
    int l = i >> 12;
    int r = i & 4095;
    int k = r >> 6;
    int nn = r & 63;
    unsigned short v;
    if (l < 3) {
      v = f32 ? f32_to_bf16u(((const float*)Ws)[l * 4096 + r])
              : ((const unsigned short*)Ws)[l * 4096 + r];
    } else {
      v = f32 ? f32_to_bf16u(((const float*)Wout)[r])
              : ((const unsigned short*)Wout)[r];
    }
    WT[l * 4096 + nn * 64 + k] = v;
  }
  // biases -> fp32
  for (int i = gid; i < 4 * 64; i += stride) {
    int l = i >> 6;
    int j = i & 63;
    float v;
    if (l < 3)
      v = f32 ? ((const float*)bs)[l * 64 + j]
              : bf16u_to_f32(((const unsigned short*)bs)[l * 64 + j]);
    else
      v = f32 ? ((const float*)bout)[j]
              : bf16u_to_f32(((const unsigned short*)bout)[j]);
    biasf[i] = v;
  }
}

// ---------------- bucketed partition (fixed-capacity regions) ----------------

__global__ __launch_bounds__(256) void k_partition(
    const void* __restrict__ ei, const int* __restrict__ flags,
    int* __restrict__ bucket_cursor, int* __restrict__ packed, int e) {
  __shared__ int lhist[512];
  __shared__ int lbase[512];
  int tid = threadIdx.x;
  int t0 = blockIdx.x * PTILE;
  int tend = min(t0 + PTILE, e);
  if (t0 >= e) return;
  int i64 = flags[1];

  for (int b = tid; b < 512; b += 256) lhist[b] = 0;
  __syncthreads();

  if (i64) {
    const long long* dst = (const long long*)ei + e;
    for (int i = t0 + tid; i < tend; i += 256)
      atomicAdd(&lhist[((int)dst[i]) >> BSHIFT], 1);
  } else {
    const int* dst = (const int*)ei + e;
    for (int i = t0 + tid; i < tend; i += 256)
      atomicAdd(&lhist[dst[i] >> BSHIFT], 1);
  }
  __syncthreads();

  for (int b = tid; b < 512; b += 256) {
    int c = lhist[b];
    lbase[b] = c ? atomicAdd(&bucket_cursor[b], c) : 0;
    lhist[b] = 0;  // reuse as rank counter
  }
  __syncthreads();

  if (i64) {
    const long long* srcp = (const long long*)ei;
    const long long* dstp = srcp + e;
    for (int i = t0 + tid; i < tend; i += 256) {
      int s = (int)srcp[i];
      int d = (int)dstp[i];
      int b = d >> BSHIFT;
      int r = atomicAdd(&lhist[b], 1);
      packed[lbase[b] + r] = (s << BSHIFT) | (d & (BNODES - 1));
    }
  } else {
    const int* srcp = (const int*)ei;
    const int* dstp = srcp + e;
    for (int i = t0 + tid; i < tend; i += 256) {
      int s = srcp[i];
      int d = dstp[i];
      int b = d >> BSHIFT;
      int r = atomicAdd(&lhist[b], 1);
      packed[lbase[b] + r] = (s << BSHIFT) | (d & (BNODES - 1));
    }
  }
}

// One block per bucket: LDS counting sort -> per-node src list (grouped by
// dst) in the bucket's csr region, rowrange (beg,end), dinv.
__global__ __launch_bounds__(256) void k_sort_csr(
    const int* __restrict__ packed, const int* __restrict__ bucket_cursor,
    int* __restrict__ csr, int2* __restrict__ rowrange,
    float* __restrict__ dinv, int n) {
  __shared__ int lcnt[BNODES];
  __shared__ int lofs[BNODES];
  __shared__ int sbuf[BNODES];
  int tid = threadIdx.x;
  int bucket = blockIdx.x;
  int node0 = bucket << BSHIFT;
  int nodes = min(BNODES, n - node0);
  int s0 = bucket * BCAP;
  int s1 = bucket_cursor[bucket];  // region end after partition
  lcnt[tid] = 0;
  __syncthreads();
  for (int i = s0 + tid; i < s1; i += 256)
    atomicAdd(&lcnt[packed[i] & (BNODES - 1)], 1);
  __syncthreads();
  int v = lcnt[tid];
  sbuf[tid] = v;
  __syncthreads();
  for (int off = 1; off < BNODES; off <<= 1) {
    int tv = (tid >= off) ? sbuf[tid - off] : 0;
    __syncthreads();
    sbuf[tid] += tv;
    __syncthreads();
  }
  int excl = sbuf[tid] - v;
  lofs[tid] = excl;
  lcnt[tid] = 0;  // reuse as rank counter
  if (tid < nodes) {
    rowrange[node0 + tid] = make_int2(s0 + excl, s0 + excl + v);
    dinv[node0 + tid] = rsqrtf((float)(v + 1));  // +1 = self loop
  }
  __syncthreads();
  for (int i = s0 + tid; i < s1; i += 256) {
    int pk = packed[i];
    int ld = pk & (BNODES - 1);
    int r = atomicAdd(&lcnt[ld], 1);
    csr[s0 + lofs[ld] + r] = pk >> BSHIFT;
  }
}

// ---------------- z0 = dinv * x0 (bf16), handles fp32/bf16 input ----------------

__global__ __launch_bounds__(256) void k_scale(
    const void* __restrict__ x0, const int* __restrict__ flags,
    const float* __restrict__ dinv, ushort4* __restrict__ z, int n16) {
  int f32 = flags[0];
  int i = blockIdx.x * 256 + threadIdx.x;
  int stride = gridDim.x * 256;
  for (; i < n16; i += stride) {
    float d = dinv[i >> 4];
    ushort4 o;
    if (f32) {
      float4 v = ((const float4*)x0)[i];
      o.x = f32_to_bf16u(d * v.x);
      o.y = f32_to_bf16u(d * v.y);
      o.z = f32_to_bf16u(d * v.z);
      o.w = f32_to_bf16u(d * v.w);
    } else {
      ushort4 v = ((const ushort4*)x0)[i];
      o.x = f32_to_bf16u(d * bf16u_to_f32(v.x));
      o.y = f32_to_bf16u(d * bf16u_to_f32(v.y));
      o.z = f32_to_bf16u(d * bf16u_to_f32(v.z));
      o.w = f32_to_bf16u(d * bf16u_to_f32(v.w));
    }
    z[i] = o;
  }
}

// ---------------- fused layer ----------------
// y = dinv_dst*(z_dst + sum z_src); out = relu(yW+b) [optionally * dinv].
// One block per 16-node tile; r6 gather/merge structure (plateau-validated:
// addr-cut r3 +15%, DS-merge r6 +10%; occupancy x2 / persistent pipeline /
// slot-table front-end / deg-skip / sc0 L1-bypass all null or negative ->
// gather throughput = shared outstanding-request capacity / L2-L3 latency).
// r11: layer 2 chains the final projection GEMM in-kernel (saved the 25MB
// x3 round-trip + launch, -8.4us). r13: ybf2 stride 80 -> 64 with 16B-
// granule XOR swizzle G = (col>>3) ^ ((row>>1)&7) on write AND read.
// r12's counters showed 1.8M bank-conflict cycles from the stride-80 ybf2:
// 4-row quarter stride (160B == 0 mod 128B) put all 4 quarters on one bank
// set (8-way b16 writes). With the XOR, per write instruction the quarters
// carry XOR values {x,x^2,x^4,x^6} and f>>3 completes all 8 granules ->
// 32 banks x 2 lanes = free; b128 reads land at exactly 8 accesses/bank.
// Spill tripwire: WRITE_SIZE ~12.5MB (L0/L1), 25MB fp32 d_out (L2).
__global__ __launch_bounds__(256, 4) void k_fused(
    const unsigned short* __restrict__ z, const int2* __restrict__ rowrange,
    const int* __restrict__ csr, const float* __restrict__ dinv,
    const unsigned short* __restrict__ WT, const float* __restrict__ biasf,
    unsigned short* __restrict__ out, int n, int scale_out,
    const unsigned short* __restrict__ WTf, const float* __restrict__ biasff,
    void* __restrict__ fout, const int* __restrict__ flags) {
  __shared__ __align__(16) float part[4 * 2048];  // [wave][node][group][ch]
  __shared__ unsigned short ybf[16 * 80];
  __shared__ __align__(16) unsigned short ybf2[16 * 64];
  int tid = threadIdx.x;
  int lane = tid & 63;
  int w = tid >> 6;   // wave id = output col-tile
  int q = lane >> 4;  // phase-2 quarter
  int f = lane & 15;  // phase-2 frag row
  int h = lane & 7;   // 16B slot within a 128B z row
  int g8 = lane >> 3; // 8-lane group = edge slot group

  // B-frags for this wave's column tile
  short8 b0 = *(const short8*)(WT + (size_t)(f + 16 * w) * 64 + q * 8);
  short8 b1 = *(const short8*)(WT + (size_t)(f + 16 * w) * 64 + 32 + q * 8);
  // final-GEMM frags (layer 2 only; wave-uniform branch)
  short8 c0 = {0, 0, 0, 0, 0, 0, 0, 0};
  short8 c1 = {0, 0, 0, 0, 0, 0, 0, 0};
  float bvf = 0.f;
  int f32o = 0;
  if (fout != nullptr) {
    c0 = *(const short8*)(WTf + (size_t)(f + 16 * w) * 64 + q * 8);
    c1 = *(const short8*)(WTf + (size_t)(f + 16 * w) * 64 + 32 + q * 8);
    bvf = biasff[16 * w + f];
    f32o = flags[0];
  }

  int row0 = blockIdx.x * 16;
  int base_node = row0 + w * 4;
  const short8* z8 = (const short8*)z;

  // --- rowrange: one 8-lane load, broadcast via shfl ---
  int rrw = 0;
  if (lane < 8) rrw = ((const int*)rowrange)[(size_t)base_node * 2 + lane];
  int rx0 = __shfl(rrw, 0, 64);
  int ry0 = __shfl(rrw, 1, 64);
  int rx1 = __shfl(rrw, 2, 64);
  int ry1 = __shfl(rrw, 3, 64);
  int rx2 = __shfl(rrw, 4, 64);
  int ry2 = __shfl(rrw, 5, 64);
  int rx3 = __shfl(rrw, 6, 64);
  int ry3 = __shfl(rrw, 7, 64);
  int deg0 = ry0 - rx0;
  int deg1 = ry1 - rx1;
  int deg2 = ry2 - rx2;
  int deg3 = ry3 - rx3;

  // --- index table: lane (jx*16+m) holds slot m of node jx ---
  // slot 0 = self, slots 1..15 = first 15 csr edges (clamped dups if short)
  int jx = lane >> 4;
  int m = lane & 15;
  int rxj = (jx & 2) ? ((jx & 1) ? rx3 : rx2) : ((jx & 1) ? rx1 : rx0);
  int dgj = (jx & 2) ? ((jx & 1) ? deg3 : deg2) : ((jx & 1) ? deg1 : deg0);
  int coff = (m >= 1 && m <= dgj) ? (m - 1) : 0;
  int idx = csr[rxj + coff];
  if (m == 0) idx = base_node + jx;

  // --- phase 1: 8 gather instrs, 8 edges each (16B/lane, 8 lanes/row) ---
  float a0[8] = {0, 0, 0, 0, 0, 0, 0, 0};
  float a1[8] = {0, 0, 0, 0, 0, 0, 0, 0};
  float a2[8] = {0, 0, 0, 0, 0, 0, 0, 0};
  float a3[8] = {0, 0, 0, 0, 0, 0, 0, 0};

  short8 g[8];
#pragma unroll
  for (int t = 0; t < 8; t++) {
    int u = ((t & 1) << 3) + g8;                 // slot 0..15
    int sl = ((t >> 1) << 4) + u;                // table holder lane
    int s = __shfl(idx, sl, 64);
    g[t] = z8[(size_t)s * 8 + h];
  }
#pragma unroll
  for (int t = 0; t < 8; t++) {
    int u = ((t & 1) << 3) + g8;
    const int j = t >> 1;
    int dg = (j == 0) ? deg0 : (j == 1) ? deg1 : (j == 2) ? deg2 : deg3;
    float vm = (u <= dg) ? 1.f : 0.f;
    float* aj = (j == 0) ? a0 : (j == 1) ? a1 : (j == 2) ? a2 : a3;
#pragma unroll
    for (int c = 0; c < 8; c++)
      aj[c] += vm * bf16u_to_f32((unsigned short)g[t][c]);
  }

  // --- rare tail: deg > 15, 8 edges per round ---
#pragma unroll
  for (int j = 0; j < 4; j++) {
    int rx = (j == 0) ? rx0 : (j == 1) ? rx1 : (j == 2) ? rx2 : rx3;
    int dg = (j == 0) ? deg0 : (j == 1) ? deg1 : (j == 2) ? deg2 : deg3;
    float* aj = (j == 0) ? a0 : (j == 1) ? a1 : (j == 2) ? a2 : a3;
    for (int e0 = 15; e0 < dg; e0 += 8) {
      int e = e0 + g8;
      bool vv = e < dg;
      int s = csr[rx + (vv ? e : 0)];
      short8 tv = z8[(size_t)s * 8 + h];
      float vm = vv ? 1.f : 0.f;
#pragma unroll
      for (int c = 0; c < 8; c++)
        aj[c] += vm * bf16u_to_f32((unsigned short)tv[c]);
    }
  }

  // --- merge the 8 groups via per-wave XOR-swizzled LDS partials ---
  // layout: byte = w*8192 + j*2048 + g*256 + ((gi ^ g) << 4), gi = ch>>2
  char* pb = (char*)part + (w << 13);
  {
    int base_wg = g8 << 8;  // g8*256
#pragma unroll
    for (int j = 0; j < 4; j++) {
      const float* aj = (j == 0) ? a0 : (j == 1) ? a1 : (j == 2) ? a2 : a3;
      int jb = j << 11;
      *(float4*)(pb + jb + base_wg + ((((2 * h) ^ g8)) << 4)) =
          make_float4(aj[0], aj[1], aj[2], aj[3]);
      *(float4*)(pb + jb + base_wg + ((((2 * h + 1) ^ g8)) << 4)) =
          make_float4(aj[4], aj[5], aj[6], aj[7]);
    }
  }
  // read back: lane -> node jr = lane>>4, channels 4*gr..4*gr+3 (gr=lane&15)
  int jr = lane >> 4;
  int gr = lane & 15;
  float s0 = 0.f, s1 = 0.f, s2 = 0.f, s3 = 0.f;
#pragma unroll
  for (int gg = 0; gg < 8; gg++) {
    float4 v = *(const float4*)(pb + (jr << 11) + (gg << 8) + ((gr ^ gg) << 4));
    s0 += v.x;
    s1 += v.y;
    s2 += v.z;
    s3 += v.w;
  }
  {
    float dv = dinv[base_node + jr];
    unsigned int w0 = (unsigned int)f32_to_bf16u(dv * s0) |
                      ((unsigned int)f32_to_bf16u(dv * s1) << 16);
    unsigned int w1 = (unsigned int)f32_to_bf16u(dv * s2) |
                      ((unsigned int)f32_to_bf16u(dv * s3) << 16);
    *(uint2*)&ybf[(w * 4 + jr) * 80 + 4 * gr] = make_uint2(w0, w1);
  }
  __syncthreads();

  // --- phase 2: MFMA yW for this wave's 16 columns ---
  short8 fa0 = *(const short8*)&ybf[f * 80 + q * 8];
  short8 fa1 = *(const short8*)&ybf[f * 80 + 32 + q * 8];
  float4v zz = {0.f, 0.f, 0.f, 0.f};
  float4v acc = __builtin_amdgcn_mfma_f32_16x16x32_bf16(fa0, b0, zz, 0, 0, 0);
  acc = __builtin_amdgcn_mfma_f32_16x16x32_bf16(fa1, b1, acc, 0, 0, 0);

  float bv = biasf[16 * w + f];
  if (fout == nullptr) {
    if (scale_out) {
      float4 dv4 = *(const float4*)(dinv + row0 + q * 4);
      float d[4] = {dv4.x, dv4.y, dv4.z, dv4.w};
#pragma unroll
      for (int reg = 0; reg < 4; reg++) {
        int row = row0 + q * 4 + reg;
        if (row < n)
          out[(size_t)row * 64 + 16 * w + f] =
              f32_to_bf16u(d[reg] * fmaxf(acc[reg] + bv, 0.f));
      }
    } else {
#pragma unroll
      for (int reg = 0; reg < 4; reg++) {
        int row = row0 + q * 4 + reg;
        if (row < n)
          out[(size_t)row * 64 + 16 * w + f] =
              f32_to_bf16u(fmaxf(acc[reg] + bv, 0.f));
      }
    }
  } else {
    // --- chained final projection: x3 -> ybf2 (XOR-swizzled), barrier,
    //     x3 @ Wout + bout -> d_out ---
#pragma unroll
    for (int reg = 0; reg < 4; reg++) {
      int r = q * 4 + reg;
      int col = 16 * w + f;
      int G = (col >> 3) ^ ((r >> 1) & 7);
      ybf2[r * 64 + G * 8 + (f & 7)] = f32_to_bf16u(fmaxf(acc[reg] + bv, 0.f));
    }
    __syncthreads();
    int fx = (f >> 1) & 7;
    short8 ga0 = *(const short8*)&ybf2[f * 64 + (q ^ fx) * 8];
    short8 ga1 = *(const short8*)&ybf2[f * 64 + ((4 + q) ^ fx) * 8];
    float4v acc2 =
        __builtin_amdgcn_mfma_f32_16x16x32_bf16(ga0, c0, zz, 0, 0, 0);
    acc2 = __builtin_amdgcn_mfma_f32_16x16x32_bf16(ga1, c1, acc2, 0, 0, 0);
    if (f32o) {
      float* op = (float*)fout;
#pragma unroll
      for (int reg = 0; reg < 4; reg++) {
        int row = row0 + q * 4 + reg;
        if (row < n) op[(size_t)row * 64 + 16 * w + f] = acc2[reg] + bvf;
      }
    } else {
      unsigned short* op = (unsigned short*)fout;
#pragma unroll
      for (int reg = 0; reg < 4; reg++) {
        int row = row0 + q * 4 + reg;
        if (row < n)
          op[(size_t)row * 64 + 16 * w + f] = f32_to_bf16u(acc2[reg] + bvf);
      }
    }
  }
}

// ---------------- launch ----------------

extern "C" void kernel_launch(void* const* d_in, const int* in_sizes, int n_in,
                              void* d_out, int out_size, void* d_ws,
                              size_t ws_size, hipStream_t stream) {
  const void* x0 = d_in[0];
  const void* ei = d_in[1];
  const void* Ws = d_in[2];
  const void* bs = d_in[3];
  const void* Wout = d_in[4];
  const void* bout = d_in[5];

  const int N = in_sizes[0] / D;  // 100000
  const int E = in_sizes[1] / 2;  // 1000000
  const int NBUC = (N + BNODES - 1) >> BSHIFT;  // 391
  const int NT = (N + 15) / 16;  // 6250 row tiles

  char* p = (char*)d_ws;
  auto alloc = [&](size_t bytes) {
    char* r = p;
    p += (bytes + 511) & ~(size_t)511;
    return r;
  };
  int* flags = (int*)alloc(8);
  int* bucket_cursor = (int*)alloc(512 * 4);
  int* packed = (int*)alloc((size_t)512 * BCAP * 4);
  int* csr = (int*)alloc((size_t)512 * BCAP * 4);
  int2* rowrange = (int2*)alloc((size_t)N * 8);
  float* dinv = (float*)alloc((size_t)N * 4);
  unsigned short* WT = (unsigned short*)alloc(4 * 4096 * 2);
  float* biasf = (float*)alloc(4 * 64 * 4);
  unsigned short* za = (unsigned short*)alloc((size_t)N * D * 2);
  unsigned short* zb = (unsigned short*)alloc((size_t)N * D * 2);
  (void)ws_size;
  (void)n_in;
  (void)out_size;

  k_probe<<<1, 64, 0, stream>>>(Ws, ei, flags);
  k_prep<<<32, 256, 0, stream>>>(Ws, Wout, bs, bout, flags, WT, biasf,
                                 bucket_cursor);
  int ptiles = (E + PTILE - 1) / PTILE;
  k_partition<<<ptiles, 256, 0, stream>>>(ei, flags, bucket_cursor, packed, E);
  k_sort_csr<<<NBUC, 256, 0, stream>>>(packed, bucket_cursor, csr, rowrange,
                                       dinv, N);
  k_scale<<<1024, 256, 0, stream>>>(x0, flags, dinv, (ushort4*)za, N * 16);

  // layer 0: za -> zb (z'), layer 1: zb -> za (z'),
  // layer 2: za -> (x3 in LDS) -> chained final GEMM -> d_out
  k_fused<<<NT, 256, 0, stream>>>(za, rowrange, csr, dinv, WT + 0 * 4096,
                                  biasf + 0 * 64, zb, N, 1, nullptr, nullptr,
                                  nullptr, flags);
  k_fused<<<NT, 256, 0, stream>>>(zb, rowrange, csr, dinv, WT + 1 * 4096,
                                  biasf + 1 * 64, za, N, 1, nullptr, nullptr,
                                  nullptr, flags);
  k_fused<<<NT, 256, 0, stream>>>(za, rowrange, csr, dinv, WT + 2 * 4096,
                                  biasf + 2 * 64, zb, N, 0, WT + 3 * 4096,
                                  biasf + 3 * 64, d_out, flags);
}

// Round 14
// 217.367 us; speedup vs baseline: 1.0609x; 1.0180x over previous
//
#include <hip/hip_runtime.h>
#include <hip/hip_bf16.h>

#define D 64
#define BSHIFT 8           // 256 nodes per bucket
#define BNODES 256
#define BCAP 4096          // edge capacity per bucket region (exp 2558, +30 sigma)
#define PTILE 2048         // edges per partition tile (489 blocks -> full CU coverage)

typedef __attribute__((ext_vector_type(8))) short short8;
typedef __attribute__((ext_vector_type(4))) float float4v;

// flags[0] = 1 if float tensors are fp32 (else bf16)
// flags[1] = 1 if edge_index is int64 (else int32)

__device__ __forceinline__ float bf16u_to_f32(unsigned short u) {
  union { unsigned int i; float f; } c;
  c.i = ((unsigned int)u) << 16;
  return c.f;
}

__device__ __forceinline__ unsigned short f32_to_bf16u(float f) {
  union { float f; unsigned int u; } c;
  c.f = f;
  unsigned int r = (c.u + 0x7fffu + ((c.u >> 16) & 1u)) >> 16;  // RNE
  return (unsigned short)r;
}

// ---------------- probe dtypes ----------------
// r12 lesson: computing these per-wave inside k_fused perturbed its codegen
// (VGPR 64->52, SGPR 48->112) and re-serialized the gather flight (+11us).
// Keep the tiny serial probe kernel.

__global__ void k_probe(const void* W, const void* ei, int* flags) {
  int lane = threadIdx.x & 63;
  const unsigned short* wb = (const unsigned short*)W;
  bool big = false;
  for (int i = lane; i < 512; i += 64) {
    float v = bf16u_to_f32(wb[i]);
    if (!(fabsf(v) < 100.f)) big = true;  // NaN lands here too
  }
  int anybig = __any(big);
  const int* e32 = (const int*)ei;
  bool nz = (e32[2 * lane + 1] != 0);  // odd words of first 64 pairs
  int anynz = __any(nz);
  if (threadIdx.x == 0) {
    flags[0] = anybig ? 1 : 0;  // huge magnitudes => data is actually fp32
    flags[1] = anynz ? 0 : 1;   // all-zero odd words => int64
  }
}

// ---------------- weight prep + cursor init (parallel) ----------------

__global__ __launch_bounds__(256) void k_prep(
    const void* __restrict__ Ws, const void* __restrict__ Wout,
    const void* __restrict__ bs, const void* __restrict__ bout,
    const int* __restrict__ flags, unsigned short* __restrict__ WT,
    float* __restrict__ biasf, int* __restrict__ bucket_cursor) {
  int f32 = flags[0];
  int gid = blockIdx.x * 256 + threadIdx.x;
  int stride = gridDim.x * 256;

  for (int i = gid; i < 512; i += stride) bucket_cursor[i] = i * BCAP;

  // transpose 4 weight matrices into WT[l][n][k] (bf16)
  for (int i = gid; i < 4 * 4096; i += stride) {
    int l = i >> 12;
    int r = i & 4095;
    int k = r >> 6;
    int nn = r & 63;
    unsigned short v;
    if (l < 3) {
      v = f32 ? f32_to_bf16u(((const float*)Ws)[l * 4096 + r])
              : ((const unsigned short*)Ws)[l * 4096 + r];
    } else {
      v = f32 ? f32_to_bf16u(((const float*)Wout)[r])
              : ((const unsigned short*)Wout)[r];
    }
    WT[l * 4096 + nn * 64 + k] = v;
  }
  // biases -> fp32
  for (int i = gid; i < 4 * 64; i += stride) {
    int l = i >> 6;
    int j = i & 63;
    float v;
    if (l < 3)
      v = f32 ? ((const float*)bs)[l * 64 + j]
              : bf16u_to_f32(((const unsigned short*)bs)[l * 64 + j]);
    else
      v = f32 ? ((const float*)bout)[j]
              : bf16u_to_f32(((const unsigned short*)bout)[j]);
    biasf[i] = v;
  }
}

// ---------------- bucketed partition (fixed-capacity regions) ----------------

__global__ __launch_bounds__(256) void k_partition(
    const void* __restrict__ ei, const int* __restrict__ flags,
    int* __restrict__ bucket_cursor, int* __restrict__ packed, int e) {
  __shared__ int lhist[512];
  __shared__ int lbase[512];
  int tid = threadIdx.x;
  int t0 = blockIdx.x * PTILE;
  int tend = min(t0 + PTILE, e);
  if (t0 >= e) return;
  int i64 = flags[1];

  for (int b = tid; b < 512; b += 256) lhist[b] = 0;
  __syncthreads();

  if (i64) {
    const long long* dst = (const long long*)ei + e;
    for (int i = t0 + tid; i < tend; i += 256)
      atomicAdd(&lhist[((int)dst[i]) >> BSHIFT], 1);
  } else {
    const int* dst = (const int*)ei + e;
    for (int i = t0 + tid; i < tend; i += 256)
      atomicAdd(&lhist[dst[i] >> BSHIFT], 1);
  }
  __syncthreads();

  for (int b = tid; b < 512; b += 256) {
    int c = lhist[b];
    lbase[b] = c ? atomicAdd(&bucket_cursor[b], c) : 0;
    lhist[b] = 0;  // reuse as rank counter
  }
  __syncthreads();

  if (i64) {
    const long long* srcp = (const long long*)ei;
    const long long* dstp = srcp + e;
    for (int i = t0 + tid; i < tend; i += 256) {
      int s = (int)srcp[i];
      int d = (int)dstp[i];
      int b = d >> BSHIFT;
      int r = atomicAdd(&lhist[b], 1);
      packed[lbase[b] + r] = (s << BSHIFT) | (d & (BNODES - 1));
    }
  } else {
    const int* srcp = (const int*)ei;
    const int* dstp = srcp + e;
    for (int i = t0 + tid; i < tend; i += 256) {
      int s = srcp[i];
      int d = dstp[i];
      int b = d >> BSHIFT;
      int r = atomicAdd(&lhist[b], 1);
      packed[lbase[b] + r] = (s << BSHIFT) | (d & (BNODES - 1));
    }
  }
}

// One block per bucket: LDS counting sort -> per-node src list (grouped by
// dst) in the bucket's csr region, rowrange (beg,end), dinv.
__global__ __launch_bounds__(256) void k_sort_csr(
    const int* __restrict__ packed, const int* __restrict__ bucket_cursor,
    int* __restrict__ csr, int2* __restrict__ rowrange,
    float* __restrict__ dinv, int n) {
  __shared__ int lcnt[BNODES];
  __shared__ int lofs[BNODES];
  __shared__ int sbuf[BNODES];
  int tid = threadIdx.x;
  int bucket = blockIdx.x;
  int node0 = bucket << BSHIFT;
  int nodes = min(BNODES, n - node0);
  int s0 = bucket * BCAP;
  int s1 = bucket_cursor[bucket];  // region end after partition
  lcnt[tid] = 0;
  __syncthreads();
  for (int i = s0 + tid; i < s1; i += 256)
    atomicAdd(&lcnt[packed[i] & (BNODES - 1)], 1);
  __syncthreads();
  int v = lcnt[tid];
  sbuf[tid] = v;
  __syncthreads();
  for (int off = 1; off < BNODES; off <<= 1) {
    int tv = (tid >= off) ? sbuf[tid - off] : 0;
    __syncthreads();
    sbuf[tid] += tv;
    __syncthreads();
  }
  int excl = sbuf[tid] - v;
  lofs[tid] = excl;
  lcnt[tid] = 0;  // reuse as rank counter
  if (tid < nodes) {
    rowrange[node0 + tid] = make_int2(s0 + excl, s0 + excl + v);
    dinv[node0 + tid] = rsqrtf((float)(v + 1));  // +1 = self loop
  }
  __syncthreads();
  for (int i = s0 + tid; i < s1; i += 256) {
    int pk = packed[i];
    int ld = pk & (BNODES - 1);
    int r = atomicAdd(&lcnt[ld], 1);
    csr[s0 + lofs[ld] + r] = pk >> BSHIFT;
  }
}

// ---------------- z0 = dinv * x0 (bf16), handles fp32/bf16 input ----------------

__global__ __launch_bounds__(256) void k_scale(
    const void* __restrict__ x0, const int* __restrict__ flags,
    const float* __restrict__ dinv, ushort4* __restrict__ z, int n16) {
  int f32 = flags[0];
  int i = blockIdx.x * 256 + threadIdx.x;
  int stride = gridDim.x * 256;
  for (; i < n16; i += stride) {
    float d = dinv[i >> 4];
    ushort4 o;
    if (f32) {
      float4 v = ((const float4*)x0)[i];
      o.x = f32_to_bf16u(d * v.x);
      o.y = f32_to_bf16u(d * v.y);
      o.z = f32_to_bf16u(d * v.z);
      o.w = f32_to_bf16u(d * v.w);
    } else {
      ushort4 v = ((const ushort4*)x0)[i];
      o.x = f32_to_bf16u(d * bf16u_to_f32(v.x));
      o.y = f32_to_bf16u(d * bf16u_to_f32(v.y));
      o.z = f32_to_bf16u(d * bf16u_to_f32(v.z));
      o.w = f32_to_bf16u(d * bf16u_to_f32(v.w));
    }
    z[i] = o;
  }
}

// ---------------- fused layer ----------------
// y = dinv_dst*(z_dst + sum z_src); out = relu(yW+b) [optionally * dinv].
// One block per 16-node tile; r6 gather/merge structure (plateau-validated:
// addr-cut r3 +15%, DS-merge r6 +10%; occupancy x2 / persistent pipeline /
// slot-table front-end / deg-skip / sc0 L1-bypass / ybf2-swizzle all null
// or negative -> gather throughput = shared outstanding-request capacity /
// L2-L3 latency; LDS conflict cycles (r12: 1.8M on layer 2) overlap with
// gather waiting and are NOT on the critical path (r13 swizzle: neutral).
// r11: layer 2 chains the final projection GEMM in-kernel (x3 -> ybf2,
// barrier, 2 MFMAs with Wout frags, store d_out) -- saved the 25MB x3
// round-trip + launch (-8.4us). This file == r11, the measured best
// (219.7us total).
// Spill tripwire: WRITE_SIZE ~12.5MB (L0/L1), 25MB fp32 d_out (L2).
__global__ __launch_bounds__(256, 4) void k_fused(
    const unsigned short* __restrict__ z, const int2* __restrict__ rowrange,
    const int* __restrict__ csr, const float* __restrict__ dinv,
    const unsigned short* __restrict__ WT, const float* __restrict__ biasf,
    unsigned short* __restrict__ out, int n, int scale_out,
    const unsigned short* __restrict__ WTf, const float* __restrict__ biasff,
    void* __restrict__ fout, const int* __restrict__ flags) {
  __shared__ __align__(16) float part[4 * 2048];  // [wave][node][group][ch]
  __shared__ unsigned short ybf[16 * 80];
  __shared__ unsigned short ybf2[16 * 80];
  int tid = threadIdx.x;
  int lane = tid & 63;
  int w = tid >> 6;   // wave id = output col-tile
  int q = lane >> 4;  // phase-2 quarter
  int f = lane & 15;  // phase-2 frag row
  int h = lane & 7;   // 16B slot within a 128B z row
  int g8 = lane >> 3; // 8-lane group = edge slot group

  // B-frags for this wave's column tile
  short8 b0 = *(const short8*)(WT + (size_t)(f + 16 * w) * 64 + q * 8);
  short8 b1 = *(const short8*)(WT + (size_t)(f + 16 * w) * 64 + 32 + q * 8);
  // final-GEMM frags (layer 2 only; wave-uniform branch)
  short8 c0 = {0, 0, 0, 0, 0, 0, 0, 0};
  short8 c1 = {0, 0, 0, 0, 0, 0, 0, 0};
  float bvf = 0.f;
  int f32o = 0;
  if (fout != nullptr) {
    c0 = *(const short8*)(WTf + (size_t)(f + 16 * w) * 64 + q * 8);
    c1 = *(const short8*)(WTf + (size_t)(f + 16 * w) * 64 + 32 + q * 8);
    bvf = biasff[16 * w + f];
    f32o = flags[0];
  }

  int row0 = blockIdx.x * 16;
  int base_node = row0 + w * 4;
  const short8* z8 = (const short8*)z;

  // --- rowrange: one 8-lane load, broadcast via shfl ---
  int rrw = 0;
  if (lane < 8) rrw = ((const int*)rowrange)[(size_t)base_node * 2 + lane];
  int rx0 = __shfl(rrw, 0, 64);
  int ry0 = __shfl(rrw, 1, 64);
  int rx1 = __shfl(rrw, 2, 64);
  int ry1 = __shfl(rrw, 3, 64);
  int rx2 = __shfl(rrw, 4, 64);
  int ry2 = __shfl(rrw, 5, 64);
  int rx3 = __shfl(rrw, 6, 64);
  int ry3 = __shfl(rrw, 7, 64);
  int deg0 = ry0 - rx0;
  int deg1 = ry1 - rx1;
  int deg2 = ry2 - rx2;
  int deg3 = ry3 - rx3;

  // --- index table: lane (jx*16+m) holds slot m of node jx ---
  // slot 0 = self, slots 1..15 = first 15 csr edges (clamped dups if short)
  int jx = lane >> 4;
  int m = lane & 15;
  int rxj = (jx & 2) ? ((jx & 1) ? rx3 : rx2) : ((jx & 1) ? rx1 : rx0);
  int dgj = (jx & 2) ? ((jx & 1) ? deg3 : deg2) : ((jx & 1) ? deg1 : deg0);
  int coff = (m >= 1 && m <= dgj) ? (m - 1) : 0;
  int idx = csr[rxj + coff];
  if (m == 0) idx = base_node + jx;

  // --- phase 1: 8 gather instrs, 8 edges each (16B/lane, 8 lanes/row) ---
  float a0[8] = {0, 0, 0, 0, 0, 0, 0, 0};
  float a1[8] = {0, 0, 0, 0, 0, 0, 0, 0};
  float a2[8] = {0, 0, 0, 0, 0, 0, 0, 0};
  float a3[8] = {0, 0, 0, 0, 0, 0, 0, 0};

  short8 g[8];
#pragma unroll
  for (int t = 0; t < 8; t++) {
    int u = ((t & 1) << 3) + g8;                 // slot 0..15
    int sl = ((t >> 1) << 4) + u;                // table holder lane
    int s = __shfl(idx, sl, 64);
    g[t] = z8[(size_t)s * 8 + h];
  }
#pragma unroll
  for (int t = 0; t < 8; t++) {
    int u = ((t & 1) << 3) + g8;
    const int j = t >> 1;
    int dg = (j == 0) ? deg0 : (j == 1) ? deg1 : (j == 2) ? deg2 : deg3;
    float vm = (u <= dg) ? 1.f : 0.f;
    float* aj = (j == 0) ? a0 : (j == 1) ? a1 : (j == 2) ? a2 : a3;
#pragma unroll
    for (int c = 0; c < 8; c++)
      aj[c] += vm * bf16u_to_f32((unsigned short)g[t][c]);
  }

  // --- rare tail: deg > 15, 8 edges per round ---
#pragma unroll
  for (int j = 0; j < 4; j++) {
    int rx = (j == 0) ? rx0 : (j == 1) ? rx1 : (j == 2) ? rx2 : rx3;
    int dg = (j == 0) ? deg0 : (j == 1) ? deg1 : (j == 2) ? deg2 : deg3;
    float* aj = (j == 0) ? a0 : (j == 1) ? a1 : (j == 2) ? a2 : a3;
    for (int e0 = 15; e0 < dg; e0 += 8) {
      int e = e0 + g8;
      bool vv = e < dg;
      int s = csr[rx + (vv ? e : 0)];
      short8 tv = z8[(size_t)s * 8 + h];
      float vm = vv ? 1.f : 0.f;
#pragma unroll
      for (int c = 0; c < 8; c++)
        aj[c] += vm * bf16u_to_f32((unsigned short)tv[c]);
    }
  }

  // --- merge the 8 groups via per-wave XOR-swizzled LDS partials ---
  // layout: byte = w*8192 + j*2048 + g*256 + ((gi ^ g) << 4), gi = ch>>2
  char* pb = (char*)part + (w << 13);
  {
    int base_wg = g8 << 8;  // g8*256
#pragma unroll
    for (int j = 0; j < 4; j++) {
      const float* aj = (j == 0) ? a0 : (j == 1) ? a1 : (j == 2) ? a2 : a3;
      int jb = j << 11;
      *(float4*)(pb + jb + base_wg + ((((2 * h) ^ g8)) << 4)) =
          make_float4(aj[0], aj[1], aj[2], aj[3]);
      *(float4*)(pb + jb + base_wg + ((((2 * h + 1) ^ g8)) << 4)) =
          make_float4(aj[4], aj[5], aj[6], aj[7]);
    }
  }
  // read back: lane -> node jr = lane>>4, channels 4*gr..4*gr+3 (gr=lane&15)
  int jr = lane >> 4;
  int gr = lane & 15;
  float s0 = 0.f, s1 = 0.f, s2 = 0.f, s3 = 0.f;
#pragma unroll
  for (int gg = 0; gg < 8; gg++) {
    float4 v = *(const float4*)(pb + (jr << 11) + (gg << 8) + ((gr ^ gg) << 4));
    s0 += v.x;
    s1 += v.y;
    s2 += v.z;
    s3 += v.w;
  }
  {
    float dv = dinv[base_node + jr];
    unsigned int w0 = (unsigned int)f32_to_bf16u(dv * s0) |
                      ((unsigned int)f32_to_bf16u(dv * s1) << 16);
    unsigned int w1 = (unsigned int)f32_to_bf16u(dv * s2) |
                      ((unsigned int)f32_to_bf16u(dv * s3) << 16);
    *(uint2*)&ybf[(w * 4 + jr) * 80 + 4 * gr] = make_uint2(w0, w1);
  }
  __syncthreads();

  // --- phase 2: MFMA yW for this wave's 16 columns ---
  short8 fa0 = *(const short8*)&ybf[f * 80 + q * 8];
  short8 fa1 = *(const short8*)&ybf[f * 80 + 32 + q * 8];
  float4v zz = {0.f, 0.f, 0.f, 0.f};
  float4v acc = __builtin_amdgcn_mfma_f32_16x16x32_bf16(fa0, b0, zz, 0, 0, 0);
  acc = __builtin_amdgcn_mfma_f32_16x16x32_bf16(fa1, b1, acc, 0, 0, 0);

  float bv = biasf[16 * w + f];
  if (fout == nullptr) {
    if (scale_out) {
      float4 dv4 = *(const float4*)(dinv + row0 + q * 4);
      float d[4] = {dv4.x, dv4.y, dv4.z, dv4.w};
#pragma unroll
      for (int reg = 0; reg < 4; reg++) {
        int row = row0 + q * 4 + reg;
        if (row < n)
          out[(size_t)row * 64 + 16 * w + f] =
              f32_to_bf16u(d[reg] * fmaxf(acc[reg] + bv, 0.f));
      }
    } else {
#pragma unroll
      for (int reg = 0; reg < 4; reg++) {
        int row = row0 + q * 4 + reg;
        if (row < n)
          out[(size_t)row * 64 + 16 * w + f] =
              f32_to_bf16u(fmaxf(acc[reg] + bv, 0.f));
      }
    }
  } else {
    // --- chained final projection: x3 -> ybf2, barrier, x3 @ Wout + bout ---
#pragma unroll
    for (int reg = 0; reg < 4; reg++) {
      int r = q * 4 + reg;
      ybf2[r * 80 + 16 * w + f] = f32_to_bf16u(fmaxf(acc[reg] + bv, 0.f));
    }
    __syncthreads();
    short8 ga0 = *(const short8*)&ybf2[f * 80 + q * 8];
    short8 ga1 = *(const short8*)&ybf2[f * 80 + 32 + q * 8];
    float4v acc2 =
        __builtin_amdgcn_mfma_f32_16x16x32_bf16(ga0, c0, zz, 0, 0, 0);
    acc2 = __builtin_amdgcn_mfma_f32_16x16x32_bf16(ga1, c1, acc2, 0, 0, 0);
    if (f32o) {
      float* op = (float*)fout;
#pragma unroll
      for (int reg = 0; reg < 4; reg++) {
        int row = row0 + q * 4 + reg;
        if (row < n) op[(size_t)row * 64 + 16 * w + f] = acc2[reg] + bvf;
      }
    } else {
      unsigned short* op = (unsigned short*)fout;
#pragma unroll
      for (int reg = 0; reg < 4; reg++) {
        int row = row0 + q * 4 + reg;
        if (row < n)
          op[(size_t)row * 64 + 16 * w + f] = f32_to_bf16u(acc2[reg] + bvf);
      }
    }
  }
}

// ---------------- launch ----------------

extern "C" void kernel_launch(void* const* d_in, const int* in_sizes, int n_in,
                              void* d_out, int out_size, void* d_ws,
                              size_t ws_size, hipStream_t stream) {
  const void* x0 = d_in[0];
  const void* ei = d_in[1];
  const void* Ws = d_in[2];
  const void* bs = d_in[3];
  const void* Wout = d_in[4];
  const void* bout = d_in[5];

  const int N = in_sizes[0] / D;  // 100000
  const int E = in_sizes[1] / 2;  // 1000000
  const int NBUC = (N + BNODES - 1) >> BSHIFT;  // 391
  const int NT = (N + 15) / 16;  // 6250 row tiles

  char* p = (char*)d_ws;
  auto alloc = [&](size_t bytes) {
    char* r = p;
    p += (bytes + 511) & ~(size_t)511;
    return r;
  };
  int* flags = (int*)alloc(8);
  int* bucket_cursor = (int*)alloc(512 * 4);
  int* packed = (int*)alloc((size_t)512 * BCAP * 4);
  int* csr = (int*)alloc((size_t)512 * BCAP * 4);
  int2* rowrange = (int2*)alloc((size_t)N * 8);
  float* dinv = (float*)alloc((size_t)N * 4);
  unsigned short* WT = (unsigned short*)alloc(4 * 4096 * 2);
  float* biasf = (float*)alloc(4 * 64 * 4);
  unsigned short* za = (unsigned short*)alloc((size_t)N * D * 2);
  unsigned short* zb = (unsigned short*)alloc((size_t)N * D * 2);
  (void)ws_size;
  (void)n_in;
  (void)out_size;

  k_probe<<<1, 64, 0, stream>>>(Ws, ei, flags);
  k_prep<<<32, 256, 0, stream>>>(Ws, Wout, bs, bout, flags, WT, biasf,
                                 bucket_cursor);
  int ptiles = (E + PTILE - 1) / PTILE;
  k_partition<<<ptiles, 256, 0, stream>>>(ei, flags, bucket_cursor, packed, E);
  k_sort_csr<<<NBUC, 256, 0, stream>>>(packed, bucket_cursor, csr, rowrange,
                                       dinv, N);
  k_scale<<<1024, 256, 0, stream>>>(x0, flags, dinv, (ushort4*)za, N * 16);

  // layer 0: za -> zb (z'), layer 1: zb -> za (z'),
  // layer 2: za -> (x3 in LDS) -> chained final GEMM -> d_out
  k_fused<<<NT, 256, 0, stream>>>(za, rowrange, csr, dinv, WT + 0 * 4096,
                                  biasf + 0 * 64, zb, N, 1, nullptr, nullptr,
                                  nullptr, flags);
  k_fused<<<NT, 256, 0, stream>>>(zb, rowrange, csr, dinv, WT + 1 * 4096,
                                  biasf + 1 * 64, za, N, 1, nullptr, nullptr,
                                  nullptr, flags);
  k_fused<<<NT, 256, 0, stream>>>(za, rowrange, csr, dinv, WT + 2 * 4096,
                                  biasf + 2 * 64, zb, N, 0, WT + 3 * 4096,
                                  biasf + 3 * 64, d_out, flags);
}